// Round 11
// baseline (148.579 us; speedup 1.0000x reference)
//
#include <hip/hip_runtime.h>

typedef float f32x4 __attribute__((ext_vector_type(4)));
typedef short bf16x8 __attribute__((ext_vector_type(8)));
typedef unsigned int u32;
typedef unsigned short u16;

constexpr int T_ = 32768;
constexpr int D_ = 2048;
constexpr int E_ = 64;
constexpr int KSEL = 6;
constexpr float ROUTE_SCALE_ = 1.0f;

constexpr int ROWS = 64;            // 4 waves x 16 rows per block
constexpr int DK = 32;              // k per chunk (= R10's kf-subchunk; same k order)
constexpr int NCH = D_ / DK;        // 64
constexpr int WBUF = 12288;         // one W chunk: 12 frags x 1KB (3 planes x 4 frags)
// LDS = 2*WBUF = 24576; logits slab (16KB) reuses wbuf after final barrier.

// round-to-nearest-even fp32 -> bf16 (same as R4/R10 -> bit-identical logits)
__device__ __forceinline__ u16 f2bf(float f) {
  u32 u = __float_as_uint(f);
  return (u16)((u + 0x7fffu + ((u >> 16) & 1u)) >> 16);
}
__device__ __forceinline__ float bf2f(u16 h) { return __uint_as_float(((u32)h) << 16); }

// ---- W pre-split (BYTES IDENTICAL TO R10's ws; indices re-expressed per DK=32) ----
// byte: c2*WBUF + (nfq*3 + p)*1024 + lane*16   (c2 = 0..63)
// lane elem j = plane_p(W[e][k]), e = nfq*16+(lane&15), k = c2*32 + (lane>>4)*8 + j
__global__ void wsplit_kernel(const float* __restrict__ W, char* __restrict__ ws) {
  int g = blockIdx.x * 256 + threadIdx.x;
  if (g >= NCH * 256) return;                  // 16384 threads
  int lane = g & 63, nfq = (g >> 6) & 3, c2 = g >> 8;
  int e = nfq * 16 + (lane & 15);
  int k0 = c2 * 32 + ((lane >> 4) << 3);
  const float* src = W + (size_t)e * D_ + k0;
  f32x4 a0 = *(const f32x4*)src;
  f32x4 a1 = *(const f32x4*)(src + 4);
  float f[8] = {a0.x, a0.y, a0.z, a0.w, a1.x, a1.y, a1.z, a1.w};
  bf16x8 h, m, l;
#pragma unroll
  for (int j = 0; j < 8; ++j) {
    u16 hb = f2bf(f[j]); float r1 = f[j] - bf2f(hb);   // exact
    u16 mb = f2bf(r1);   float r2 = r1 - bf2f(mb);     // exact
    u16 lb = f2bf(r2);
    h[j] = (short)hb; m[j] = (short)mb; l[j] = (short)lb;
  }
  char* dst = ws + (size_t)c2 * WBUF + (size_t)(nfq * 3) * 1024 + lane * 16;
  *(bf16x8*)(dst)        = h;
  *(bf16x8*)(dst + 1024) = m;
  *(bf16x8*)(dst + 2048) = l;
}

__device__ __forceinline__ void gload16(const void* g, void* l) {
  __builtin_amdgcn_global_load_lds(
      (const __attribute__((address_space(1))) void*)g,
      (__attribute__((address_space(3))) void*)l, 16, 0, 0);
}

__launch_bounds__(256, 5)
__global__ void gate_kernel(const float* __restrict__ x, const char* __restrict__ ws,
                            float* __restrict__ out) {
  __shared__ __align__(16) char sm[2 * WBUF];   // 24576 B -> 5 blocks/CU

  const int tid = threadIdx.x;
  const int lane = tid & 63;
  const int wv = tid >> 6;                 // 0..3, wave owns rows [wv*16, wv*16+16)
  const int r0 = blockIdx.x * ROWS;

  // per-lane x base: row = r0 + wv*16 + (lane&15), k-offset (lane>>4)*8
  const float* xp = x + (size_t)(r0 + wv * 16 + (lane & 15)) * D_ + ((lane >> 4) << 3);

  f32x4 xA[2], xB[2];                      // two static reg banks (chunk c, c+1)

#define XLOAD(BANK, C)                                            \
  { const float* p_ = xp + (size_t)(C) * DK;                      \
    BANK[0] = *(const f32x4*)(p_); BANK[1] = *(const f32x4*)(p_ + 4); }

  // LDS dst wave-uniform (HW adds lane*16); global src per-lane. 3 insts/thread.
  auto wgload = [&](int c) {
    const char* src = ws + (size_t)c * WBUF + (size_t)tid * 16;     // per-lane
    char* dstb = sm + (c & 1) * WBUF + (size_t)(wv * 64) * 16;      // wave-uniform
#pragma unroll
    for (int it = 0; it < 3; ++it)
      gload16(src + it * 4096, dstb + it * 4096);
  };

  f32x4 acc[4] = {};                       // 4 expert-quadrants x 4 regs

  // split one reg bank (8 floats) + 24 MFMA against wbuf[c&1]; same value/op order as R10
#define STEP(BANK, C)                                                          \
  {                                                                            \
    bf16x8 ah, am, al;                                                         \
    {                                                                          \
      f32x4 a0 = BANK[0], a1 = BANK[1];                                        \
      float f[8] = {a0.x, a0.y, a0.z, a0.w, a1.x, a1.y, a1.z, a1.w};           \
      _Pragma("unroll")                                                        \
      for (int j = 0; j < 8; ++j) {                                            \
        float v = f[j];                                                        \
        u32 uh = __float_as_uint(v) & 0xffff0000u;                             \
        float r1 = v - __uint_as_float(uh);                                    \
        u32 um = __float_as_uint(r1) & 0xffff0000u;                            \
        float r2 = r1 - __uint_as_float(um);                                   \
        u32 ul = __float_as_uint(r2);                                          \
        ah[j] = (short)(uh >> 16);                                             \
        am[j] = (short)(um >> 16);                                             \
        al[j] = (short)(ul >> 16);                                             \
      }                                                                        \
    }                                                                          \
    const char* wb = sm + ((C) & 1) * WBUF + lane * 16;                        \
    _Pragma("unroll")                                                          \
    for (int n = 0; n < 4; ++n) {                                              \
      const char* fb = wb + (size_t)(n * 3) * 1024;                            \
      bf16x8 bh = *(const bf16x8*)(fb);                                        \
      bf16x8 bm = *(const bf16x8*)(fb + 1024);                                 \
      bf16x8 bl = *(const bf16x8*)(fb + 2048);                                 \
      f32x4 c_ = acc[n];                                                       \
      c_ = __builtin_amdgcn_mfma_f32_16x16x32_bf16(al, bh, c_, 0, 0, 0);       \
      c_ = __builtin_amdgcn_mfma_f32_16x16x32_bf16(am, bm, c_, 0, 0, 0);       \
      c_ = __builtin_amdgcn_mfma_f32_16x16x32_bf16(ah, bl, c_, 0, 0, 0);       \
      c_ = __builtin_amdgcn_mfma_f32_16x16x32_bf16(am, bh, c_, 0, 0, 0);       \
      c_ = __builtin_amdgcn_mfma_f32_16x16x32_bf16(ah, bm, c_, 0, 0, 0);       \
      c_ = __builtin_amdgcn_mfma_f32_16x16x32_bf16(ah, bh, c_, 0, 0, 0);       \
      acc[n] = c_;                                                             \
    }                                                                          \
  }

  // prologue: x chunks 0,1 to reg banks; W chunk 0 to LDS buf0
  XLOAD(xA, 0)
  XLOAD(xB, 1)
  wgload(0);

  // main loop: one __syncthreads per chunk; every load it drains is >=1 phase old
  for (int cc = 0; cc < NCH; cc += 2) {
    __syncthreads();                       // W(cc) + x-bank loads landed
    if (cc + 1 < NCH) wgload(cc + 1);      // -> wbuf1 (last read compute(cc-1), drained)
    STEP(xA, cc)                           // compute chunk cc from wbuf0
    if (cc + 2 < NCH) XLOAD(xA, cc + 2)
    __syncthreads();                       // W(cc+1) landed
    if (cc + 2 < NCH) wgload(cc + 2);      // -> wbuf0
    STEP(xB, cc + 1)                       // compute chunk cc+1 from wbuf1
    if (cc + 3 < NCH) XLOAD(xB, cc + 3)
  }

  // ---- logits into LDS (reuses wbuf; all STEP reads done -> barrier first) ----
  __syncthreads();
  float* slab = (float*)sm + wv * 16 * E_;   // wave-private 16-row slab
#pragma unroll
  for (int n = 0; n < 4; ++n)
#pragma unroll
    for (int j = 0; j < 4; ++j) {
      int r = ((lane >> 4) << 2) + j;
      slab[r * 64 + n * 16 + (lane & 15)] = acc[n][j];
    }

  // ---- proven top-k epilogue: lane = expert, 16 rows per wave ----
  float* outI = out;
  float* outW = out + (size_t)T_ * KSEL;
  for (int rr = 0; rr < 16; ++rr) {
    const float lg = slab[rr * 64 + lane];
    float mx = lg;
#pragma unroll
    for (int off = 32; off; off >>= 1) mx = fmaxf(mx, __shfl_xor(mx, off, 64));
    const float p = expf(lg - mx);
    float ssum = p;
#pragma unroll
    for (int off = 32; off; off >>= 1) ssum += __shfl_xor(ssum, off, 64);
    float prob = p / ssum;

    const int rg = r0 + wv * 16 + rr;
#pragma unroll
    for (int kk = 0; kk < KSEL; ++kk) {
      float v = prob; int idx = lane;
#pragma unroll
      for (int off = 32; off; off >>= 1) {
        float ov = __shfl_xor(v, off, 64);
        int oi = __shfl_xor(idx, off, 64);
        if (ov > v || (ov == v && oi < idx)) { v = ov; idx = oi; }
      }
      const float wsel = __shfl(lg, idx, 64);
      if (lane == 0) {
        outI[(size_t)rg * KSEL + kk] = (float)idx;
        outW[(size_t)rg * KSEL + kk] = wsel * ROUTE_SCALE_;
      }
      if (lane == idx) prob = -1.0f;
    }
  }
#undef XLOAD
#undef STEP
}

extern "C" void kernel_launch(void* const* d_in, const int* in_sizes, int n_in,
                              void* d_out, int out_size, void* d_ws, size_t ws_size,
                              hipStream_t stream) {
  const float* x = (const float*)d_in[0];
  const float* W = (const float*)d_in[1];
  char* ws = (char*)d_ws;                  // 64 * 12288 = 786432 bytes
  float* out = (float*)d_out;
  wsplit_kernel<<<dim3(64), dim3(256), 0, stream>>>(W, ws);
  gate_kernel<<<dim3(T_ / ROWS), dim3(256), 0, stream>>>(x, ws, out);
}

// Round 12
// 99.912 us; speedup vs baseline: 1.4871x; 1.4871x over previous
//
#include <hip/hip_runtime.h>

typedef float f32x4 __attribute__((ext_vector_type(4)));
typedef short bf16x8 __attribute__((ext_vector_type(8)));
typedef unsigned int u32;
typedef unsigned short u16;

constexpr int T_ = 32768;
constexpr int D_ = 2048;
constexpr int E_ = 64;
constexpr int KSEL = 6;
constexpr float ROUTE_SCALE_ = 1.0f;

constexpr int ROWS = 64;            // rows per block; 8 waves = 4 row-groups x 2 K-halves
constexpr int DK = 32;              // k per chunk
constexpr int NCHH = 1024 / DK;     // 32 chunks per K-half
constexpr int WBUF = 12288;         // one W chunk: 12 frags x 1KB (3 planes x 4 frags)
constexpr int HSTRIDE = 2 * WBUF;   // per-half dbuf region; LDS total = 49152

// round-to-nearest-even fp32 -> bf16 (unbiased; same split values as R4/R10)
__device__ __forceinline__ u16 f2bf(float f) {
  u32 u = __float_as_uint(f);
  return (u16)((u + 0x7fffu + ((u >> 16) & 1u)) >> 16);
}
__device__ __forceinline__ float bf2f(u16 h) { return __uint_as_float(((u32)h) << 16); }

// ---- W pre-split (bytes identical to R10/R11's ws) ----
// byte: c2*WBUF + (nfq*3 + p)*1024 + lane*16   (c2 = 0..63)
// lane elem j = plane_p(W[e][k]), e = nfq*16+(lane&15), k = c2*32 + (lane>>4)*8 + j
__global__ void wsplit_kernel(const float* __restrict__ W, char* __restrict__ ws) {
  int g = blockIdx.x * 256 + threadIdx.x;
  if (g >= 64 * 256) return;                   // 16384 threads
  int lane = g & 63, nfq = (g >> 6) & 3, c2 = g >> 8;
  int e = nfq * 16 + (lane & 15);
  int k0 = c2 * 32 + ((lane >> 4) << 3);
  const float* src = W + (size_t)e * D_ + k0;
  f32x4 a0 = *(const f32x4*)src;
  f32x4 a1 = *(const f32x4*)(src + 4);
  float f[8] = {a0.x, a0.y, a0.z, a0.w, a1.x, a1.y, a1.z, a1.w};
  bf16x8 h, m, l;
#pragma unroll
  for (int j = 0; j < 8; ++j) {
    u16 hb = f2bf(f[j]); float r1 = f[j] - bf2f(hb);   // exact
    u16 mb = f2bf(r1);   float r2 = r1 - bf2f(mb);     // exact
    u16 lb = f2bf(r2);
    h[j] = (short)hb; m[j] = (short)mb; l[j] = (short)lb;
  }
  char* dst = ws + (size_t)c2 * WBUF + (size_t)(nfq * 3) * 1024 + lane * 16;
  *(bf16x8*)(dst)        = h;
  *(bf16x8*)(dst + 1024) = m;
  *(bf16x8*)(dst + 2048) = l;
}

__device__ __forceinline__ void gload16(const void* g, void* l) {
  __builtin_amdgcn_global_load_lds(
      (const __attribute__((address_space(1))) void*)g,
      (__attribute__((address_space(3))) void*)l, 16, 0, 0);
}

__launch_bounds__(512, 4)
__global__ void gate_kernel(const float* __restrict__ x, const char* __restrict__ ws,
                            float* __restrict__ out) {
  __shared__ __align__(16) char sm[2 * HSTRIDE];   // 49152 B

  const int tid = threadIdx.x;
  const int lane = tid & 63;
  const int wv = tid >> 6;                 // 0..7
  const int half = wv >> 2;                // K-half: k in [half*1024, half*1024+1024)
  const int wl = wv & 3;                   // row group: rows [wl*16, wl*16+16)
  const int r0 = blockIdx.x * ROWS;

  // per-lane x base: row = r0 + wl*16 + (lane&15), k = half*1024 + (lane>>4)*8
  const float* xp = x + (size_t)(r0 + wl * 16 + (lane & 15)) * D_
                      + half * 1024 + ((lane >> 4) << 3);

  f32x4 xA[2], xB[2];                      // two static reg banks (chunk c2, c2+1)

#define XLOAD(BANK, C)                                            \
  { const float* p_ = xp + (size_t)(C) * DK;                      \
    BANK[0] = *(const f32x4*)(p_); BANK[1] = *(const f32x4*)(p_ + 4); }

  // per-half staging: 4 waves of the half co-stage its 12KB chunk.
  // LDS dst wave-uniform (HW adds lane*16); global src per-lane.
  auto wgload = [&](int c2) {
    const char* src = ws + (size_t)(half * NCHH + c2) * WBUF
                         + (size_t)(wl * 64 + lane) * 16;               // per-lane
    char* dstb = sm + half * HSTRIDE + (c2 & 1) * WBUF + (size_t)(wl * 64) * 16;  // uniform
#pragma unroll
    for (int it = 0; it < 3; ++it)
      gload16(src + it * 4096, dstb + it * 4096);
  };

  f32x4 acc[4] = {};                       // 4 expert-quadrants x 4 regs

  // split one reg bank (8 floats) + 24 MFMA against this half's wbuf[c&1]
#define STEP(BANK, C)                                                          \
  {                                                                            \
    bf16x8 ah, am, al;                                                         \
    {                                                                          \
      f32x4 a0 = BANK[0], a1 = BANK[1];                                        \
      float f[8] = {a0.x, a0.y, a0.z, a0.w, a1.x, a1.y, a1.z, a1.w};           \
      _Pragma("unroll")                                                        \
      for (int j = 0; j < 8; ++j) {                                            \
        float v = f[j];                                                        \
        u32 uh = __float_as_uint(v) & 0xffff0000u;                             \
        float r1 = v - __uint_as_float(uh);                                    \
        u32 um = __float_as_uint(r1) & 0xffff0000u;                            \
        float r2 = r1 - __uint_as_float(um);                                   \
        u32 ul = __float_as_uint(r2);                                          \
        ah[j] = (short)(uh >> 16);                                             \
        am[j] = (short)(um >> 16);                                             \
        al[j] = (short)(ul >> 16);                                             \
      }                                                                        \
    }                                                                          \
    const char* wb = sm + half * HSTRIDE + ((C) & 1) * WBUF + lane * 16;       \
    _Pragma("unroll")                                                          \
    for (int n = 0; n < 4; ++n) {                                              \
      const char* fb = wb + (size_t)(n * 3) * 1024;                            \
      bf16x8 bh = *(const bf16x8*)(fb);                                        \
      bf16x8 bm = *(const bf16x8*)(fb + 1024);                                 \
      bf16x8 bl = *(const bf16x8*)(fb + 2048);                                 \
      f32x4 c_ = acc[n];                                                       \
      c_ = __builtin_amdgcn_mfma_f32_16x16x32_bf16(al, bh, c_, 0, 0, 0);       \
      c_ = __builtin_amdgcn_mfma_f32_16x16x32_bf16(am, bm, c_, 0, 0, 0);       \
      c_ = __builtin_amdgcn_mfma_f32_16x16x32_bf16(ah, bl, c_, 0, 0, 0);       \
      c_ = __builtin_amdgcn_mfma_f32_16x16x32_bf16(am, bh, c_, 0, 0, 0);       \
      c_ = __builtin_amdgcn_mfma_f32_16x16x32_bf16(ah, bm, c_, 0, 0, 0);       \
      c_ = __builtin_amdgcn_mfma_f32_16x16x32_bf16(ah, bh, c_, 0, 0, 0);       \
      acc[n] = c_;                                                             \
    }                                                                          \
  }

  // prologue: x chunks 0,1 of this half; W chunk 0 of this half
  XLOAD(xA, 0)
  XLOAD(xB, 1)
  wgload(0);

  // main loop (32 chunks per half, in lockstep across halves):
  // one __syncthreads per chunk; every load it drains is >=1 phase old
  for (int cc = 0; cc < NCHH; cc += 2) {
    __syncthreads();
    if (cc + 1 < NCHH) wgload(cc + 1);
    STEP(xA, cc)
    if (cc + 2 < NCHH) XLOAD(xA, cc + 2)
    __syncthreads();
    if (cc + 2 < NCHH) wgload(cc + 2);
    STEP(xB, cc + 1)
    if (cc + 3 < NCHH) XLOAD(xB, cc + 3)
  }

  // ---- partial logits to LDS: SL[half][row][e], 32KB (reuses wbuf region) ----
  __syncthreads();                         // all STEP reads of wbuf done
  float* SL = (float*)sm;
#pragma unroll
  for (int n = 0; n < 4; ++n)
#pragma unroll
    for (int j = 0; j < 4; ++j) {
      int r = wl * 16 + ((lane >> 4) << 2) + j;
      SL[half * (ROWS * E_) + r * E_ + n * 16 + (lane & 15)] = acc[n][j];
    }
  __syncthreads();

  // ---- reduce halves + proven top-k epilogue: 8 rows per wave, lane = expert ----
  float* outI = out;
  float* outW = out + (size_t)T_ * KSEL;
  for (int rr = 0; rr < 8; ++rr) {
    const int r = wv * 8 + rr;
    const float lg = SL[r * E_ + lane] + SL[ROWS * E_ + r * E_ + lane];
    float mx = lg;
#pragma unroll
    for (int off = 32; off; off >>= 1) mx = fmaxf(mx, __shfl_xor(mx, off, 64));
    const float p = expf(lg - mx);
    float ssum = p;
#pragma unroll
    for (int off = 32; off; off >>= 1) ssum += __shfl_xor(ssum, off, 64);
    float prob = p / ssum;

    const int rg = r0 + r;
#pragma unroll
    for (int kk = 0; kk < KSEL; ++kk) {
      float v = prob; int idx = lane;
#pragma unroll
      for (int off = 32; off; off >>= 1) {
        float ov = __shfl_xor(v, off, 64);
        int oi = __shfl_xor(idx, off, 64);
        if (ov > v || (ov == v && oi < idx)) { v = ov; idx = oi; }
      }
      const float wsel = __shfl(lg, idx, 64);
      if (lane == 0) {
        outI[(size_t)rg * KSEL + kk] = (float)idx;
        outW[(size_t)rg * KSEL + kk] = wsel * ROUTE_SCALE_;
      }
      if (lane == idx) prob = -1.0f;
    }
  }
#undef XLOAD
#undef STEP
}

extern "C" void kernel_launch(void* const* d_in, const int* in_sizes, int n_in,
                              void* d_out, int out_size, void* d_ws, size_t ws_size,
                              hipStream_t stream) {
  const float* x = (const float*)d_in[0];
  const float* W = (const float*)d_in[1];
  char* ws = (char*)d_ws;                  // 64 * 12288 = 786432 bytes
  float* out = (float*)d_out;
  wsplit_kernel<<<dim3(64), dim3(256), 0, stream>>>(W, ws);
  gate_kernel<<<dim3(T_ / ROWS), dim3(512), 0, stream>>>(x, ws, out);
}